// Round 1
// baseline (1638.013 us; speedup 1.0000x reference)
//
#include <hip/hip_runtime.h>

// SimpleGNN: 2-layer GCN on MI355X.
// Inputs (d_in order): x[100000,64] f32, W1[64,64] f32, b1[64] f32,
//                      W2[64,10] f32, b2[10] f32, edge_index[2,1600000] int32.
// Output: [100000,10] f32.
//
// Decomposition (PyG GCNConv = D^-1/2 (A+I) D^-1/2 (x W) + b):
//   deg[i]  = 1 + #in-edges(i)        (self-loop included)
//   dis[i]  = rsqrt(deg[i])
//   h1s     = dis * (x @ W1)          (pre-scaled; also seeds acc1 = self-loop term)
//   acc1   += scatter-add over edges of h1s[src]
//   layer1  = dis * acc1 + b1         (fused into GEMM2 load)
//   h2s     = dis * (layer1 @ W2)     (seeds out)
//   out    += scatter-add of h2s[src]
//   out     = dis * out + b2

#define NN 100000
#define NE 1600000

__global__ void k_init_deg(float* __restrict__ deg) {
    int i = blockIdx.x * blockDim.x + threadIdx.x;
    if (i < NN) deg[i] = 1.0f;  // self loop
}

__global__ void k_count_deg(const int* __restrict__ dst, float* __restrict__ deg) {
    int e = blockIdx.x * blockDim.x + threadIdx.x;
    if (e < NE) unsafeAtomicAdd(&deg[dst[e]], 1.0f);
}

__global__ void k_dis(const float* __restrict__ deg, float* __restrict__ dis) {
    int i = blockIdx.x * blockDim.x + threadIdx.x;
    if (i < NN) dis[i] = rsqrtf(deg[i]);
}

// h1s[i][c] = dis[i] * sum_k x[i][k] * W1[k][c]; also writes acc1 = h1s (self term).
__global__ __launch_bounds__(256) void k_gemm1(const float* __restrict__ x,
                                               const float* __restrict__ W1,
                                               const float* __restrict__ dis,
                                               float* __restrict__ h1s,
                                               float* __restrict__ acc1) {
    __shared__ float Wl[64 * 64];
    __shared__ float xr[4][64];
    for (int i = threadIdx.x; i < 64 * 64; i += 256) Wl[i] = W1[i];
    __syncthreads();
    const int g = threadIdx.x >> 6;   // row sub-group 0..3
    const int c = threadIdx.x & 63;   // output channel
    for (int base = blockIdx.x * 4; base < NN; base += gridDim.x * 4) {
        int row = base + g;           // NN % 4 == 0, always valid
        xr[g][c] = x[row * 64 + c];
        __syncthreads();
        float acc = 0.f;
        #pragma unroll
        for (int k = 0; k < 64; ++k) acc = fmaf(xr[g][k], Wl[k * 64 + c], acc);
        float v = acc * dis[row];
        h1s[row * 64 + c]  = v;
        acc1[row * 64 + c] = v;
        __syncthreads();
    }
}

// Edge scatter, layer 1: 16 threads per edge, float4 gather + 4 scalar atomics.
__global__ void k_agg1(const int* __restrict__ src, const int* __restrict__ dst,
                       const float* __restrict__ h1s, float* __restrict__ acc1) {
    int w = blockIdx.x * blockDim.x + threadIdx.x;  // < NE*16 = 25.6M
    if (w >= NE * 16) return;
    int e = w >> 4, q = w & 15;
    int s = src[e], d = dst[e];
    float4 v = *(const float4*)&h1s[s * 64 + q * 4];
    float* p = &acc1[d * 64 + q * 4];
    unsafeAtomicAdd(p + 0, v.x);
    unsafeAtomicAdd(p + 1, v.y);
    unsafeAtomicAdd(p + 2, v.z);
    unsafeAtomicAdd(p + 3, v.w);
}

// h2s[i][c] = dis[i] * sum_k (dis[i]*acc1[i][k] + b1[k]) * W2[k][c]; seeds out = h2s.
__global__ __launch_bounds__(256) void k_gemm2(const float* __restrict__ acc1,
                                               const float* __restrict__ W2,
                                               const float* __restrict__ b1,
                                               const float* __restrict__ dis,
                                               float* __restrict__ h2s,
                                               float* __restrict__ out) {
    __shared__ float W2l[64 * 10];
    __shared__ float b1l[64];
    __shared__ float tile[64][65];
    for (int i = threadIdx.x; i < 640; i += 256) W2l[i] = W2[i];
    if (threadIdx.x < 64) b1l[threadIdx.x] = b1[threadIdx.x];
    __syncthreads();
    for (int base = blockIdx.x * 64; base < NN; base += gridDim.x * 64) {
        int nrows = min(64, NN - base);
        for (int i = threadIdx.x; i < nrows * 64; i += 256) {
            int r = i >> 6, k = i & 63;
            tile[r][k] = dis[base + r] * acc1[(base + r) * 64 + k] + b1l[k];
        }
        __syncthreads();
        for (int o = threadIdx.x; o < nrows * 10; o += 256) {
            int r = o / 10, c = o - r * 10;
            float acc = 0.f;
            #pragma unroll
            for (int k = 0; k < 64; ++k) acc = fmaf(tile[r][k], W2l[k * 10 + c], acc);
            float v = acc * dis[base + r];
            h2s[(base + r) * 10 + c] = v;
            out[(base + r) * 10 + c] = v;
        }
        __syncthreads();
    }
}

// Edge scatter, layer 2: one thread per (edge, channel), 10 channels.
__global__ void k_agg2(const int* __restrict__ src, const int* __restrict__ dst,
                       const float* __restrict__ h2s, float* __restrict__ out) {
    int w = blockIdx.x * blockDim.x + threadIdx.x;  // < NE*10 = 16M
    if (w >= NE * 10) return;
    int e = w / 10, c = w - e * 10;
    int s = src[e], d = dst[e];
    unsafeAtomicAdd(&out[d * 10 + c], h2s[s * 10 + c]);
}

__global__ void k_final(const float* __restrict__ dis, const float* __restrict__ b2,
                        float* __restrict__ out) {
    int i = blockIdx.x * blockDim.x + threadIdx.x;
    if (i >= NN * 10) return;
    int r = i / 10, c = i - r * 10;
    out[i] = dis[r] * out[i] + b2[c];
}

extern "C" void kernel_launch(void* const* d_in, const int* in_sizes, int n_in,
                              void* d_out, int out_size, void* d_ws, size_t ws_size,
                              hipStream_t stream) {
    const float* x  = (const float*)d_in[0];
    const float* W1 = (const float*)d_in[1];
    const float* b1 = (const float*)d_in[2];
    const float* W2 = (const float*)d_in[3];
    const float* b2 = (const float*)d_in[4];
    const int* edge = (const int*)d_in[5];   // [2, NE] flat: src row then dst row
    const int* src = edge;
    const int* dst = edge + NE;
    float* out = (float*)d_out;

    // Workspace layout (floats): deg[NN] | dis[NN] | h1s[NN*64] | acc1[NN*64] | h2s[NN*10]
    float* ws   = (float*)d_ws;
    float* deg  = ws;
    float* dis  = ws + 100000;
    float* h1s  = ws + 200000;
    float* acc1 = ws + 200000 + 6400000;
    float* h2s  = ws + 200000 + 2 * 6400000;
    // total 14.0M floats = 56 MB

    k_init_deg<<<(NN + 255) / 256, 256, 0, stream>>>(deg);
    k_count_deg<<<(NE + 255) / 256, 256, 0, stream>>>(dst, deg);
    k_dis<<<(NN + 255) / 256, 256, 0, stream>>>(deg, dis);
    k_gemm1<<<4096, 256, 0, stream>>>(x, W1, dis, h1s, acc1);
    k_agg1<<<(NE * 16) / 256, 256, 0, stream>>>(src, dst, h1s, acc1);
    k_gemm2<<<(NN + 63) / 64, 256, 0, stream>>>(acc1, W2, b1, dis, h2s, out);
    k_agg2<<<(NE * 10 + 255) / 256, 256, 0, stream>>>(src, dst, h2s, out);
    k_final<<<(NN * 10 + 255) / 256, 256, 0, stream>>>(dis, b2, out);
}

// Round 2
// 428.509 us; speedup vs baseline: 3.8226x; 3.8226x over previous
//
#include <hip/hip_runtime.h>

// SimpleGNN 2-layer GCN, atomic-free aggregation via per-call CSR build.
//
// Math (linearity lets us aggregate BEFORE projecting):
//   dis[i]   = rsqrt(1 + in_deg(i))
//   aggx[i]  = sum_{j in N(i) U {i}} dis[j] * x[j]          (gather from input x)
//   layer1   = dis * (aggx @ W1) + b1                       (in-place on aggx)
//   h2s[i]   = dis[i] * (layer1[i] @ W2)
//   out[i]   = dis[i] * (h2s[i] + sum_{j in N(i)} h2s[j]) + b2
//
// CSR build per call (kernel_launch must be stateless): histogram in-degrees,
// two-level exclusive scan, scatter src ids into dst-sorted order.

#define NN 100000
#define NE 1600000
#define SCAN_CHUNK 1024
#define NB_SCAN 98   // ceil(NN / 1024)

__global__ void k_zero_cnt(int* __restrict__ cnt) {
    int i = blockIdx.x * blockDim.x + threadIdx.x;
    if (i < NN) cnt[i] = 0;
}

__global__ void k_count(const int* __restrict__ dst, int* __restrict__ cnt) {
    int e = blockIdx.x * blockDim.x + threadIdx.x;
    if (e < NE) atomicAdd(&cnt[dst[e]], 1);
}

// Per-chunk totals: block b reduces cnt[b*1024 .. b*1024+1023].
__global__ __launch_bounds__(256) void k_scan_block(const int* __restrict__ cnt,
                                                    int* __restrict__ bsum) {
    __shared__ int sc[256];
    int t = threadIdx.x;
    int i0 = blockIdx.x * SCAN_CHUNK + t * 4;
    int s = 0;
    #pragma unroll
    for (int k = 0; k < 4; ++k) { int i = i0 + k; if (i < NN) s += cnt[i]; }
    sc[t] = s; __syncthreads();
    for (int off = 128; off > 0; off >>= 1) {
        if (t < off) sc[t] += sc[t + off];
        __syncthreads();
    }
    if (t == 0) bsum[blockIdx.x] = sc[0];
}

// Exclusive scan of the 98 chunk totals; also pin rowptr[NN] = NE.
__global__ __launch_bounds__(128) void k_scan_tops(const int* __restrict__ bsum,
                                                   int* __restrict__ boff,
                                                   int* __restrict__ rowptr) {
    __shared__ int sc[128];
    int t = threadIdx.x;
    int v = (t < NB_SCAN) ? bsum[t] : 0;
    sc[t] = v; __syncthreads();
    for (int off = 1; off < 128; off <<= 1) {
        int a = (t >= off) ? sc[t - off] : 0;
        __syncthreads();
        sc[t] += a;
        __syncthreads();
    }
    if (t < NB_SCAN) boff[t] = sc[t] - v;   // exclusive
    if (t == 0) rowptr[NN] = NE;
}

// Final: exclusive scan within each chunk + chunk offset -> rowptr, cursor.
// Also computes dis[i] = rsqrt(cnt[i] + 1) while cnt is hot.
__global__ __launch_bounds__(256) void k_scan_final(const int* __restrict__ cnt,
                                                    const int* __restrict__ boff,
                                                    int* __restrict__ rowptr,
                                                    int* __restrict__ cursor,
                                                    float* __restrict__ dis) {
    __shared__ int sc[256];
    int t = threadIdx.x;
    int i0 = blockIdx.x * SCAN_CHUNK + t * 4;
    int v[4]; int s = 0;
    #pragma unroll
    for (int k = 0; k < 4; ++k) { int i = i0 + k; v[k] = (i < NN) ? cnt[i] : 0; s += v[k]; }
    sc[t] = s; __syncthreads();
    for (int off = 1; off < 256; off <<= 1) {
        int a = (t >= off) ? sc[t - off] : 0;
        __syncthreads();
        sc[t] += a;
        __syncthreads();
    }
    int pre = boff[blockIdx.x] + sc[t] - s;   // exclusive prefix for element i0
    #pragma unroll
    for (int k = 0; k < 4; ++k) {
        int i = i0 + k;
        if (i < NN) {
            rowptr[i] = pre;
            cursor[i] = pre;
            dis[i] = rsqrtf((float)v[k] + 1.0f);
            pre += v[k];
        }
    }
}

__global__ void k_scatter(const int* __restrict__ src, const int* __restrict__ dst,
                          int* __restrict__ cursor, int* __restrict__ ssrc) {
    int e = blockIdx.x * blockDim.x + threadIdx.x;
    if (e < NE) {
        int p = atomicAdd(&cursor[dst[e]], 1);
        ssrc[p] = src[e];
    }
}

// One wave per node, lane = channel. aggx[n][c] = dis[n]*x[n][c] + sum dis[s]*x[s][c].
__global__ __launch_bounds__(256) void k_agg1(const float* __restrict__ x,
                                              const float* __restrict__ dis,
                                              const int* __restrict__ rowptr,
                                              const int* __restrict__ ssrc,
                                              float* __restrict__ aggx) {
    int g = blockIdx.x * blockDim.x + threadIdx.x;
    int n = g >> 6, lane = g & 63;
    if (n >= NN) return;
    int beg = rowptr[n], end = rowptr[n + 1];
    float acc0 = dis[n] * x[n * 64 + lane];
    float acc1 = 0.f;
    int j = beg;
    for (; j + 1 < end; j += 2) {
        int s0 = ssrc[j], s1 = ssrc[j + 1];
        float d0 = dis[s0], d1 = dis[s1];
        acc0 = fmaf(d0, x[s0 * 64 + lane], acc0);
        acc1 = fmaf(d1, x[s1 * 64 + lane], acc1);
    }
    if (j < end) {
        int s0 = ssrc[j];
        acc0 = fmaf(dis[s0], x[s0 * 64 + lane], acc0);
    }
    aggx[n * 64 + lane] = acc0 + acc1;
}

// In-place: aggx[r] <- dis[r]*(aggx[r] @ W1) + b1, 64 rows per block.
__global__ __launch_bounds__(256) void k_gemm1(float* __restrict__ aggx,
                                               const float* __restrict__ W1,
                                               const float* __restrict__ b1,
                                               const float* __restrict__ dis) {
    __shared__ float Wl[64 * 64];
    __shared__ float tile[64][65];
    for (int i = threadIdx.x; i < 64 * 64; i += 256) Wl[i] = W1[i];
    int base = blockIdx.x * 64;
    int nrows = min(64, NN - base);
    for (int i = threadIdx.x; i < nrows * 64; i += 256) {
        int r = i >> 6, k = i & 63;
        tile[r][k] = aggx[(base + r) * 64 + k];
    }
    __syncthreads();
    int c = threadIdx.x & 63, g = threadIdx.x >> 6;
    float bc = b1[c];
    for (int r = g; r < nrows; r += 4) {
        float acc = 0.f;
        #pragma unroll
        for (int k = 0; k < 64; ++k) acc = fmaf(tile[r][k], Wl[k * 64 + c], acc);
        aggx[(base + r) * 64 + c] = fmaf(dis[base + r], acc, bc);
    }
}

// h2s[r] = dis[r] * (layer1[r] @ W2), 64 rows per block, 10 out channels.
__global__ __launch_bounds__(256) void k_gemm2(const float* __restrict__ layer1,
                                               const float* __restrict__ W2,
                                               const float* __restrict__ dis,
                                               float* __restrict__ h2s) {
    __shared__ float Wl[64 * 10];
    __shared__ float tile[64][65];
    for (int i = threadIdx.x; i < 640; i += 256) Wl[i] = W2[i];
    int base = blockIdx.x * 64;
    int nrows = min(64, NN - base);
    for (int i = threadIdx.x; i < nrows * 64; i += 256) {
        int r = i >> 6, k = i & 63;
        tile[r][k] = layer1[(base + r) * 64 + k];
    }
    __syncthreads();
    for (int o = threadIdx.x; o < nrows * 10; o += 256) {
        int r = o / 10, c = o - r * 10;
        float acc = 0.f;
        #pragma unroll
        for (int k = 0; k < 64; ++k) acc = fmaf(tile[r][k], Wl[k * 10 + c], acc);
        h2s[(base + r) * 10 + c] = dis[base + r] * acc;
    }
}

// out[n][c] = dis[n]*(h2s[n][c] + sum_src h2s[s][c]) + b2[c]; 16 threads/node.
__global__ __launch_bounds__(256) void k_agg2(const float* __restrict__ h2s,
                                              const float* __restrict__ dis,
                                              const int* __restrict__ rowptr,
                                              const int* __restrict__ ssrc,
                                              const float* __restrict__ b2,
                                              float* __restrict__ out) {
    int t = blockIdx.x * blockDim.x + threadIdx.x;
    int n = t >> 4, c = t & 15;
    if (n >= NN || c >= 10) return;
    int beg = rowptr[n], end = rowptr[n + 1];
    float acc = h2s[n * 10 + c];
    for (int j = beg; j < end; ++j) {
        int s = ssrc[j];
        acc += h2s[s * 10 + c];
    }
    out[n * 10 + c] = fmaf(dis[n], acc, b2[c]);
}

extern "C" void kernel_launch(void* const* d_in, const int* in_sizes, int n_in,
                              void* d_out, int out_size, void* d_ws, size_t ws_size,
                              hipStream_t stream) {
    const float* x  = (const float*)d_in[0];
    const float* W1 = (const float*)d_in[1];
    const float* b1 = (const float*)d_in[2];
    const float* W2 = (const float*)d_in[3];
    const float* b2 = (const float*)d_in[4];
    const int* edge = (const int*)d_in[5];   // [2, NE]: src row then dst row
    const int* src = edge;
    const int* dst = edge + NE;
    float* out = (float*)d_out;

    // Workspace layout (64B-aligned offsets), total ~37.6 MB:
    char* W = (char*)d_ws;
    float* aggx   = (float*)(W);                         // NN*64 f = 25,600,000 B
    float* h2s    = (float*)(W + 25600000);              // NN*10 f =  4,000,000 B
    float* dis    = (float*)(W + 29600000);              // NN f    =    400,000 B
    int*   rowptr = (int*)  (W + 30000000);              // NN+1    =    400,004 B
    int*   cursor = (int*)  (W + 30400064);              // NN      =    400,000 B
    int*   cnt    = (int*)  (W + 30800064);              // NN      =    400,000 B
    int*   ssrc   = (int*)  (W + 31200064);              // NE      =  6,400,000 B
    int*   bsum   = (int*)  (W + 37600064);              // 98
    int*   boff   = (int*)  (W + 37600576);              // 98

    k_zero_cnt  <<<(NN + 255) / 256, 256, 0, stream>>>(cnt);
    k_count     <<<(NE + 255) / 256, 256, 0, stream>>>(dst, cnt);
    k_scan_block<<<NB_SCAN, 256, 0, stream>>>(cnt, bsum);
    k_scan_tops <<<1, 128, 0, stream>>>(bsum, boff, rowptr);
    k_scan_final<<<NB_SCAN, 256, 0, stream>>>(cnt, boff, rowptr, cursor, dis);
    k_scatter   <<<(NE + 255) / 256, 256, 0, stream>>>(src, dst, cursor, ssrc);
    k_agg1      <<<(NN * 64) / 256 + 1, 256, 0, stream>>>(x, dis, rowptr, ssrc, aggx);
    k_gemm1     <<<(NN + 63) / 64, 256, 0, stream>>>(aggx, W1, b1, dis);
    k_gemm2     <<<(NN + 63) / 64, 256, 0, stream>>>(aggx, W2, dis, h2s);
    k_agg2      <<<(NN * 16) / 256, 256, 0, stream>>>(h2s, dis, rowptr, ssrc, b2, out);
}

// Round 3
// 296.288 us; speedup vs baseline: 5.5285x; 1.4463x over previous
//
#include <hip/hip_runtime.h>

// SimpleGNN 2-layer GCN — fully linear, so collapse:
//   out = N^2 x (W1 W2) + (N 1)(b1^T W2) + 1 b2^T,   N = D^-1/2 (A+I) D^-1/2
// Project to 10 channels FIRST (W12 = W1@W2), then aggregate twice at width
// 10 (rows padded to 16 floats = 1 cache line; dis folded in; N*1 rides as
// channel 10). CSR (dst-sorted src list) built per call: histogram -> scan ->
// scatter.

#define NN 100000
#define NE 1600000
#define SCAN_CHUNK 1024
#define NB_SCAN 98   // ceil(NN / 1024)

__global__ void k_zero_cnt(int* __restrict__ cnt) {
    int i = blockIdx.x * blockDim.x + threadIdx.x;
    if (i < NN) cnt[i] = 0;
}

__global__ void k_count(const int* __restrict__ dst, int* __restrict__ cnt) {
    int e = blockIdx.x * blockDim.x + threadIdx.x;
    if (e < NE) atomicAdd(&cnt[dst[e]], 1);
}

__global__ __launch_bounds__(256) void k_scan_block(const int* __restrict__ cnt,
                                                    int* __restrict__ bsum) {
    __shared__ int sc[256];
    int t = threadIdx.x;
    int i0 = blockIdx.x * SCAN_CHUNK + t * 4;
    int s = 0;
    #pragma unroll
    for (int k = 0; k < 4; ++k) { int i = i0 + k; if (i < NN) s += cnt[i]; }
    sc[t] = s; __syncthreads();
    for (int off = 128; off > 0; off >>= 1) {
        if (t < off) sc[t] += sc[t + off];
        __syncthreads();
    }
    if (t == 0) bsum[blockIdx.x] = sc[0];
}

__global__ __launch_bounds__(128) void k_scan_tops(const int* __restrict__ bsum,
                                                   int* __restrict__ boff,
                                                   int* __restrict__ rowptr) {
    __shared__ int sc[128];
    int t = threadIdx.x;
    int v = (t < NB_SCAN) ? bsum[t] : 0;
    sc[t] = v; __syncthreads();
    for (int off = 1; off < 128; off <<= 1) {
        int a = (t >= off) ? sc[t - off] : 0;
        __syncthreads();
        sc[t] += a;
        __syncthreads();
    }
    if (t < NB_SCAN) boff[t] = sc[t] - v;
    if (t == 0) rowptr[NN] = NE;
}

__global__ __launch_bounds__(256) void k_scan_final(const int* __restrict__ cnt,
                                                    const int* __restrict__ boff,
                                                    int* __restrict__ rowptr,
                                                    int* __restrict__ cursor,
                                                    float* __restrict__ dis) {
    __shared__ int sc[256];
    int t = threadIdx.x;
    int i0 = blockIdx.x * SCAN_CHUNK + t * 4;
    int v[4]; int s = 0;
    #pragma unroll
    for (int k = 0; k < 4; ++k) { int i = i0 + k; v[k] = (i < NN) ? cnt[i] : 0; s += v[k]; }
    sc[t] = s; __syncthreads();
    for (int off = 1; off < 256; off <<= 1) {
        int a = (t >= off) ? sc[t - off] : 0;
        __syncthreads();
        sc[t] += a;
        __syncthreads();
    }
    int pre = boff[blockIdx.x] + sc[t] - s;
    #pragma unroll
    for (int k = 0; k < 4; ++k) {
        int i = i0 + k;
        if (i < NN) {
            rowptr[i] = pre;
            cursor[i] = pre;
            dis[i] = rsqrtf((float)v[k] + 1.0f);
            pre += v[k];
        }
    }
}

__global__ void k_scatter(const int* __restrict__ src, const int* __restrict__ dst,
                          int* __restrict__ cursor, int* __restrict__ ssrc) {
    int e = blockIdx.x * blockDim.x + threadIdx.x;
    if (e < NE) {
        int p = atomicAdd(&cursor[dst[e]], 1);
        ssrc[p] = src[e];
    }
}

// W12[64][10] = W1 @ W2 ; c1[10] = b1 @ W2. One block.
__global__ __launch_bounds__(256) void k_small(const float* __restrict__ W1,
                                               const float* __restrict__ W2,
                                               const float* __restrict__ b1,
                                               float* __restrict__ W12,
                                               float* __restrict__ c1) {
    int t = threadIdx.x;
    for (int o = t; o < 640; o += 256) {
        int k = o / 10, c = o - k * 10;
        float acc = 0.f;
        #pragma unroll
        for (int m = 0; m < 64; ++m) acc = fmaf(W1[k * 64 + m], W2[m * 10 + c], acc);
        W12[o] = acc;
    }
    if (t < 10) {
        float acc = 0.f;
        #pragma unroll
        for (int m = 0; m < 64; ++m) acc = fmaf(b1[m], W2[m * 10 + t], acc);
        c1[t] = acc;
    }
}

// yd[r][c] = dis[r] * (x[r] @ W12)[c], c<10; yd[r][10] = dis[r]. Row stride 16.
__global__ __launch_bounds__(256) void k_proj(const float* __restrict__ x,
                                              const float* __restrict__ W12,
                                              const float* __restrict__ dis,
                                              float* __restrict__ yd) {
    __shared__ float Wl[640];
    __shared__ float tile[64][65];
    for (int i = threadIdx.x; i < 640; i += 256) Wl[i] = W12[i];
    int base = blockIdx.x * 64;
    int nrows = min(64, NN - base);
    for (int i = threadIdx.x; i < nrows * 64; i += 256) {
        int r = i >> 6, k = i & 63;
        tile[r][k] = x[(base + r) * 64 + k];
    }
    __syncthreads();
    for (int o = threadIdx.x; o < nrows * 10; o += 256) {
        int r = o / 10, c = o - r * 10;
        float acc = 0.f;
        #pragma unroll
        for (int k = 0; k < 64; ++k) acc = fmaf(tile[r][k], Wl[k * 10 + c], acc);
        yd[(base + r) * 16 + c] = dis[base + r] * acc;
    }
    if (threadIdx.x < nrows) yd[(base + threadIdx.x) * 16 + 10] = dis[base + threadIdx.x];
}

// Pass 1: zd[n][c] = dis^2 * (yd[n][c] + sum_s yd[s][c]) for c<10;
//         zd[n][10] = n1 = dis * (yd[n][10] + sum_s yd[s][10]).
__global__ __launch_bounds__(256) void k_aggA(const float* __restrict__ yd,
                                              const float* __restrict__ dis,
                                              const int* __restrict__ rowptr,
                                              const int* __restrict__ ssrc,
                                              float* __restrict__ zd) {
    int t = blockIdx.x * blockDim.x + threadIdx.x;   // grid exact: NN*16
    int n = t >> 4, lane = t & 15;
    int beg = rowptr[n], end = rowptr[n + 1];
    float acc0 = yd[n * 16 + lane];   // self term (dis folded in)
    float acc1 = 0.f;
    int j = beg;
    for (; j + 1 < end; j += 2) {
        int s0 = ssrc[j], s1 = ssrc[j + 1];
        acc0 += yd[s0 * 16 + lane];
        acc1 += yd[s1 * 16 + lane];
    }
    if (j < end) acc0 += yd[ssrc[j] * 16 + lane];
    if (lane < 11) {
        float d = dis[n];
        float scale = (lane == 10) ? d : d * d;
        zd[n * 16 + lane] = scale * (acc0 + acc1);
    }
}

// Pass 2: out[n][c] = dis[n]*(zd[n][c] + sum_s zd[s][c]) + n1[n]*c1[c] + b2[c].
__global__ __launch_bounds__(256) void k_aggB(const float* __restrict__ zd,
                                              const float* __restrict__ dis,
                                              const int* __restrict__ rowptr,
                                              const int* __restrict__ ssrc,
                                              const float* __restrict__ c1,
                                              const float* __restrict__ b2,
                                              float* __restrict__ out) {
    int t = blockIdx.x * blockDim.x + threadIdx.x;
    int n = t >> 4, lane = t & 15;
    int beg = rowptr[n], end = rowptr[n + 1];
    float acc0 = zd[n * 16 + lane];   // self term
    float acc1 = 0.f;
    int j = beg;
    for (; j + 1 < end; j += 2) {
        int s0 = ssrc[j], s1 = ssrc[j + 1];
        acc0 += zd[s0 * 16 + lane];
        acc1 += zd[s1 * 16 + lane];
    }
    if (j < end) acc0 += zd[ssrc[j] * 16 + lane];
    if (lane < 10) {
        float n1 = zd[n * 16 + 10];
        out[n * 10 + lane] = fmaf(dis[n], acc0 + acc1, fmaf(n1, c1[lane], b2[lane]));
    }
}

extern "C" void kernel_launch(void* const* d_in, const int* in_sizes, int n_in,
                              void* d_out, int out_size, void* d_ws, size_t ws_size,
                              hipStream_t stream) {
    const float* x  = (const float*)d_in[0];
    const float* W1 = (const float*)d_in[1];
    const float* b1 = (const float*)d_in[2];
    const float* W2 = (const float*)d_in[3];
    const float* b2 = (const float*)d_in[4];
    const int* edge = (const int*)d_in[5];   // [2, NE]: src row then dst row
    const int* src = edge;
    const int* dst = edge + NE;
    float* out = (float*)d_out;

    // Workspace layout (64B-aligned), total ~20.8 MB:
    char* W = (char*)d_ws;
    float* yd     = (float*)(W);                    // NN*16 f = 6,400,000 B
    float* zd     = (float*)(W + 6400000);          // NN*16 f = 6,400,000 B
    float* dis    = (float*)(W + 12800000);         // NN f    =   400,000 B
    int*   rowptr = (int*)  (W + 13200000);         // NN+1
    int*   cursor = (int*)  (W + 13600064);         // NN
    int*   cnt    = (int*)  (W + 14000064);         // NN
    int*   ssrc   = (int*)  (W + 14400064);         // NE = 6,400,000 B
    int*   bsum   = (int*)  (W + 20800064);         // 98
    int*   boff   = (int*)  (W + 20800576);         // 98
    float* W12    = (float*)(W + 20801088);         // 640 f
    float* c1     = (float*)(W + 20803648);         // 10 f

    k_zero_cnt  <<<(NN + 255) / 256, 256, 0, stream>>>(cnt);
    k_count     <<<(NE + 255) / 256, 256, 0, stream>>>(dst, cnt);
    k_small     <<<1, 256, 0, stream>>>(W1, W2, b1, W12, c1);
    k_scan_block<<<NB_SCAN, 256, 0, stream>>>(cnt, bsum);
    k_scan_tops <<<1, 128, 0, stream>>>(bsum, boff, rowptr);
    k_scan_final<<<NB_SCAN, 256, 0, stream>>>(cnt, boff, rowptr, cursor, dis);
    k_scatter   <<<(NE + 255) / 256, 256, 0, stream>>>(src, dst, cursor, ssrc);
    k_proj      <<<(NN + 63) / 64, 256, 0, stream>>>(x, W12, dis, yd);
    k_aggA      <<<(NN * 16) / 256, 256, 0, stream>>>(yd, dis, rowptr, ssrc, zd);
    k_aggB      <<<(NN * 16) / 256, 256, 0, stream>>>(zd, dis, rowptr, ssrc, c1, b2, out);
}